// Round 4
// baseline (288.996 us; speedup 1.0000x reference)
//
#include <hip/hip_runtime.h>
#include <hip/hip_bf16.h>

#define B_ 32
#define S_ 2048
#define D_ 512
#define M_ (B_*S_)   // 65536 rows

typedef __bf16 bf16x8 __attribute__((ext_vector_type(8)));
typedef float  f32x4  __attribute__((ext_vector_type(4)));

__device__ __forceinline__ float tanh_fast(float x){
  float e2 = __expf(2.f * x);                    // inf for large x -> rcp=0 -> 1
  return 1.f - 2.f * __builtin_amdgcn_rcpf(e2 + 1.f);
}

__device__ __forceinline__ void gl_lds16(const void* g, void* l){
  __builtin_amdgcn_global_load_lds(
      (const __attribute__((address_space(1))) unsigned int*)g,
      (__attribute__((address_space(3))) unsigned int*)l, 16, 0, 0);
}

__device__ __forceinline__ bf16x8 cvt8(f32x4 a, f32x4 b){
  bf16x8 t;
  t[0]=(__bf16)a[0]; t[1]=(__bf16)a[1]; t[2]=(__bf16)a[2]; t[3]=(__bf16)a[3];
  t[4]=(__bf16)b[0]; t[5]=(__bf16)b[1]; t[6]=(__bf16)b[2]; t[7]=(__bf16)b[3];
  return t;
}

// ---- reorder w_v (fp32 KxN row-major [e*512+d]) into bf16 MFMA B-frag order ----
// frag f = ks*32 + nt. lane holds B[k = ks*32 + quad*8 + j][n = nt*16 + lm], j=0..7.
__global__ void k_reorder_wv(const float* __restrict__ wv,
                             unsigned short* __restrict__ wvr){
  int frag = blockIdx.x;          // 0..511
  int lane = threadIdx.x;         // 0..63
  int ks = frag >> 5, nt = frag & 31;
  int k0 = ks*32 + (lane>>4)*8;
  int d  = nt*16 + (lane&15);
  bf16x8 t;
  #pragma unroll
  for (int j=0;j<8;++j) t[j] = (__bf16)wv[(k0+j)*D_ + d];
  *reinterpret_cast<uint4*>(wvr + ((size_t)frag*64 + lane)*8) =
      __builtin_bit_cast(uint4, t);
}

// ---- qproj[b,d] = query[b,:] @ w_q[:,d] + bias[d]  (fp32, 4-way K-split) ----
__global__ void k_qproj(const float* __restrict__ q,
                        const float* __restrict__ wq,
                        const float* __restrict__ bias,
                        float* __restrict__ qp){
  int b  = blockIdx.y;
  int t  = threadIdx.x;          // 512
  int dl = t & 127, eg = t >> 7;
  int d  = blockIdx.x*128 + dl;
  __shared__ float qs[D_];
  __shared__ float red[4][128];
  for (int e=t; e<D_; e+=512) qs[e] = q[b*D_+e];
  __syncthreads();
  float acc = 0.f;
  #pragma unroll 8
  for (int i=0;i<128;++i){
    int e = eg*128 + i;
    acc = fmaf(qs[e], wq[(size_t)e*D_+d], acc);
  }
  red[eg][dl] = acc;
  __syncthreads();
  if (eg == 0)
    qp[b*D_+d] = red[0][dl]+red[1][dl]+red[2][dl]+red[3][dl] + bias[d];
}

// ---- fused (value@w_v + qproj + loc) -> tanh -> dot(score_w) -> partial scores ----
// Block: 128 rows x 256 cols, 4 waves. Wave w: wh=w&1 row-half, wc=w>>1 col-half;
// per wave 4 mt x 8 ntl of 16x16x32 bf16 MFMA (validated core).
// A: fp32 global -> regs -> cvt -> LDS (lane-contiguous writes, frag order).
// B: wvr frags DMA'd to LDS via global_load_lds (16B), shared by all 4 waves.
__launch_bounds__(256, 2)
__global__ void k_energy(const float* __restrict__ value,
                         const unsigned short* __restrict__ wvr,
                         const float* __restrict__ qp,
                         const float* __restrict__ energy,
                         const float* __restrict__ conv_w,
                         const float* __restrict__ conv_b,
                         const float* __restrict__ score_w,
                         float* __restrict__ scores_part){
  const int t    = threadIdx.x;
  const int wave = t >> 6;
  const int lane = t & 63;
  const int quad = lane >> 4;
  const int lm   = lane & 15;
  const int wh   = wave & 1;      // row half (64 rows)
  const int wc   = wave >> 1;     // col half (128 cols)

  const int rowtile = blockIdx.x >> 1;
  const int colh    = blockIdx.x & 1;       // 0/1 -> cols [0,256) / [256,512)
  const int row0 = rowtile * 128;
  const int b    = row0 >> 11;              // 128 | 2048
  const int s0   = row0 & (S_-1);

  // LDS: A frag-order bf16, beta = mt8*64 + koct4*16 + lm16 (16B blocks); 8KB/buf
  //      B frags lf(16) x 1KB; 16KB/buf
  __shared__ __align__(16) unsigned short As[2][4096];
  __shared__ __align__(16) unsigned short Bs[2][8192];

  // A staging map: thread t covers beta1=t, beta2=t+256
  const int bmt = t >> 6, bo = (t >> 4) & 3;
  const int blm = t & 15;
  const float* gA1 = value + (size_t)(row0 + bmt*16 + blm)*D_ + bo*8;
  const float* gA2 = gA1 + (size_t)64*D_;

  f32x4 acc[4][8];
  #pragma unroll
  for (int mt=0;mt<4;++mt)
    #pragma unroll
    for (int nt=0;nt<8;++nt)
      acc[mt][nt] = (f32x4){0.f,0.f,0.f,0.f};

  // prologue: stage kc=0
  {
    #pragma unroll
    for (int i=0;i<4;++i){
      int lf = wave*4 + i;
      int frag = 0*32 + colh*16 + lf;
      gl_lds16((const char*)wvr + (size_t)frag*1024 + lane*16,
               (char*)&Bs[0][0] + lf*1024);
    }
    f32x4 p0 = *reinterpret_cast<const f32x4*>(gA1);
    f32x4 p1 = *reinterpret_cast<const f32x4*>(gA1+4);
    f32x4 p2 = *reinterpret_cast<const f32x4*>(gA2);
    f32x4 p3 = *reinterpret_cast<const f32x4*>(gA2+4);
    *reinterpret_cast<uint4*>(&As[0][(size_t)t*8])       = __builtin_bit_cast(uint4, cvt8(p0,p1));
    *reinterpret_cast<uint4*>(&As[0][(size_t)(t+256)*8]) = __builtin_bit_cast(uint4, cvt8(p2,p3));
  }
  __syncthreads();

  for (int kc=0; kc<16; ++kc){
    const int buf = kc & 1;
    // B prefetch (DMA) for kc+1 into buf^1
    if (kc < 15){
      #pragma unroll
      for (int i=0;i<4;++i){
        int lf = wave*4 + i;
        int frag = (kc+1)*32 + colh*16 + lf;
        gl_lds16((const char*)wvr + (size_t)frag*1024 + lane*16,
                 (char*)&Bs[buf^1][0] + lf*1024);
      }
    }
    // A prefetch for kc+1 into regs
    f32x4 n0,n1,n2,n3;
    if (kc < 15){
      n0 = *reinterpret_cast<const f32x4*>(gA1 + (kc+1)*32);
      n1 = *reinterpret_cast<const f32x4*>(gA1 + (kc+1)*32 + 4);
      n2 = *reinterpret_cast<const f32x4*>(gA2 + (kc+1)*32);
      n3 = *reinterpret_cast<const f32x4*>(gA2 + (kc+1)*32 + 4);
    }
    // compute from buf
    bf16x8 a[4];
    #pragma unroll
    for (int mt=0;mt<4;++mt)
      a[mt] = *reinterpret_cast<const bf16x8*>(
                &As[buf][(size_t)(((wh*4+mt)*64 + quad*16 + lm))*8]);
    #pragma unroll
    for (int ntl=0;ntl<8;++ntl){
      bf16x8 bf = *reinterpret_cast<const bf16x8*>(
                    &Bs[buf][(size_t)((wc*8+ntl)*64 + lane)*8]);
      #pragma unroll
      for (int mt=0;mt<4;++mt)
        acc[mt][ntl] = __builtin_amdgcn_mfma_f32_16x16x32_bf16(a[mt], bf, acc[mt][ntl], 0,0,0);
    }
    // A stage into buf^1
    if (kc < 15){
      *reinterpret_cast<uint4*>(&As[buf^1][(size_t)t*8])       = __builtin_bit_cast(uint4, cvt8(n0,n1));
      *reinterpret_cast<uint4*>(&As[buf^1][(size_t)(t+256)*8]) = __builtin_bit_cast(uint4, cvt8(n2,n3));
    }
    __syncthreads();
  }

  // epilogue: per-lane d = colh*256 + wc*128 + ntl*16 + lm
  float sw[8], c0[8], c1[8], c2[8], cb[8], qv[8];
  #pragma unroll
  for (int ntl=0; ntl<8; ++ntl){
    int d = colh*256 + wc*128 + ntl*16 + lm;
    sw[ntl] = score_w[d];
    c0[ntl] = conv_w[d*3+0];
    c1[ntl] = conv_w[d*3+1];
    c2[ntl] = conv_w[d*3+2];
    cb[ntl] = conv_b[d];
    qv[ntl] = qp[b*D_+d];
  }
  float* red = (float*)&As[0][0];   // [4 waves][64 rows]
  const float* eB = energy + b*S_;
  #pragma unroll
  for (int mt=0; mt<4; ++mt){
    #pragma unroll
    for (int r=0;r<4;++r){
      int sl = wh*64 + mt*16 + quad*4 + r;      // C/D layout: row=quad*4+reg
      int s  = s0 + sl;
      float em1 = (s > 0)    ? eB[s-1] : 0.f;
      float e0  =              eB[s];
      float ep1 = (s < S_-1) ? eB[s+1] : 0.f;
      float p = 0.f;
      #pragma unroll
      for (int ntl=0; ntl<8; ++ntl){
        float h = acc[mt][ntl][r] + qv[ntl]
                + fmaf(c0[ntl],em1, fmaf(c1[ntl],e0, fmaf(c2[ntl],ep1, cb[ntl])));
        p = fmaf(sw[ntl], tanh_fast(h), p);
      }
      #pragma unroll
      for (int m=1; m<16; m<<=1) p += __shfl_xor(p, m, 64);   // reduce 16 cols
      if (lm == 0) red[wave*64 + (sl & 63)] = p;
    }
  }
  __syncthreads();
  if (t < 128){
    int half = t >> 6;
    scores_part[colh*M_ + row0 + t] = red[half*1 + (t&63) + 0] // wc=0 wave = half
                                    ;
  }
  // (indexing note: wave w = wc*2+wh; row-half h partials live in red[h] and red[2+h])
  if (t < 128){
    int half = t >> 6;
    float v0 = red[half*64 + (t&63)];
    float v1 = red[(2+half)*64 + (t&63)];
    scores_part[colh*M_ + row0 + t] = v0 + v1;
  }
}

// ---- softmax over S per batch (sums 2 col-half partials); writes align to d_out ----
__global__ void k_softmax(const float* __restrict__ sp,
                          const float* __restrict__ score_b,
                          float* __restrict__ out_align){
  int b = blockIdx.x, t = threadIdx.x;
  int lane = t & 63, wid = t >> 6;
  float sb = score_b[0];
  float v[8], mx = -3.4e38f;
  #pragma unroll
  for (int i=0;i<8;++i){
    int s = t + i*256;
    float sc = sp[b*S_+s] + sp[M_ + b*S_+s] + sb;
    v[i] = sc;
    mx = fmaxf(mx, sc);
  }
  __shared__ float red[4], red2[4];
  #pragma unroll
  for (int m=1;m<64;m<<=1) mx = fmaxf(mx, __shfl_xor(mx, m, 64));
  if (lane==0) red[wid] = mx;
  __syncthreads();
  mx = fmaxf(fmaxf(red[0],red[1]), fmaxf(red[2],red[3]));
  float sum = 0.f;
  #pragma unroll
  for (int i=0;i<8;++i){ v[i] = __expf(v[i]-mx); sum += v[i]; }
  #pragma unroll
  for (int m=1;m<64;m<<=1) sum += __shfl_xor(sum, m, 64);
  if (lane==0) red2[wid] = sum;
  __syncthreads();
  sum = red2[0]+red2[1]+red2[2]+red2[3];
  float inv = 1.f/sum;
  #pragma unroll
  for (int i=0;i<8;++i) out_align[b*S_ + t + i*256] = v[i]*inv;
}

// ---- context partials: block (sc,b) covers 128 s rows; 512 thr, unroll 8 ----
__global__ void k_ctx_part(const float* __restrict__ value,
                           const float* __restrict__ align,
                           float* __restrict__ cpart){
  int b = blockIdx.y, sc = blockIdx.x;
  int t = threadIdx.x;
  int r = t >> 7;            // 0..3 (s subgroup)
  int c = (t & 127) * 4;     // d base, 16B per thread
  f32x4 acc = (f32x4){0.f,0.f,0.f,0.f};
  #pragma unroll 8
  for (int i=0;i<32;++i){
    int s = sc*128 + i*4 + r;
    float al = align[b*S_+s];
    f32x4 v = *reinterpret_cast<const f32x4*>(value + ((size_t)(b*S_+s))*D_ + c);
    acc += al * v;
  }
  __shared__ float lred[4][D_];
  #pragma unroll
  for (int j=0;j<4;++j) lred[r][c+j] = acc[j];
  __syncthreads();
  if (r == 0){
    #pragma unroll
    for (int j=0;j<4;++j)
      cpart[((size_t)(b*16+sc))*D_ + c + j] =
          lred[0][c+j] + lred[1][c+j] + lred[2][c+j] + lred[3][c+j];
  }
}

__global__ void k_ctx_reduce(const float* __restrict__ cpart,
                             float* __restrict__ out_ctx){
  int idx = blockIdx.x*256 + threadIdx.x;   // 0..16383
  int b = idx >> 9, d = idx & 511;
  float s = 0.f;
  #pragma unroll
  for (int j=0;j<16;++j) s += cpart[((size_t)(b*16+j))*D_ + d];
  out_ctx[idx] = s;
}

extern "C" void kernel_launch(void* const* d_in, const int* in_sizes, int n_in,
                              void* d_out, int out_size, void* d_ws, size_t ws_size,
                              hipStream_t stream){
  const float* query   = (const float*)d_in[0];
  const float* value   = (const float*)d_in[1];
  const float* energy  = (const float*)d_in[2];
  const float* conv_w  = (const float*)d_in[3];
  const float* conv_b  = (const float*)d_in[4];
  const float* w_q     = (const float*)d_in[5];
  const float* w_v     = (const float*)d_in[6];
  const float* bias    = (const float*)d_in[7];
  const float* score_w = (const float*)d_in[8];
  const float* score_b = (const float*)d_in[9];

  char* ws = (char*)d_ws;
  unsigned short* wvr = (unsigned short*)(ws);            // 512 KB (bf16 frags)
  float* qp    = (float*)(ws + (512<<10));                // 64 KB
  float* sp    = (float*)(ws + (576<<10));                // 512 KB (2 x 65536 f32)
  float* cpart = (float*)(ws + (1088<<10));               // 1 MB (32*16 x 512 f32)
  // total ~2.1 MB

  float* out_ctx   = (float*)d_out;                       // [B, D] fp32
  float* out_align = out_ctx + B_*D_;                     // [B, S] fp32

  k_reorder_wv<<<dim3(512),      dim3(64),  0, stream>>>(w_v, wvr);
  k_qproj     <<<dim3(4,32),     dim3(512), 0, stream>>>(query, w_q, bias, qp);
  k_energy    <<<dim3(M_/128*2), dim3(256), 0, stream>>>(value, wvr, qp, energy,
                                                         conv_w, conv_b, score_w, sp);
  k_softmax   <<<dim3(B_),       dim3(256), 0, stream>>>(sp, score_b, out_align);
  k_ctx_part  <<<dim3(16,B_),    dim3(512), 0, stream>>>(value, out_align, cpart);
  k_ctx_reduce<<<dim3(B_*D_/256),dim3(256), 0, stream>>>(cpart, out_ctx);
}